// Round 9
// baseline (3000.488 us; speedup 1.0000x reference)
//
#include <hip/hip_runtime.h>
#include <hip/hip_cooperative_groups.h>
#include <math.h>

namespace cg = cooperative_groups;

// TrajectoryLSTM — R9: ONE persistent cooperative kernel (256 blocks x 512 thr,
// 1 block/CU guaranteed co-resident). grid.sync() replaces the 26-dispatch
// chain; the BN grid dependencies (hp stats per step, se stats per step) are
// the only cross-block data and go through f64 device atomics + agent-scope
// atomic loads. h / lastpos / c are BLOCK-LOCAL (blocks pinned to CUs).
// SE stats via 5 batch moments of lastpos (t(j) linear in x,y -> sum/sumsq
// derived exactly in f64). Final decode LSTM (outputs unused) skipped.
// Weights: R8's verified 3-way split-bf16 / 6-product MFMA scheme (fp32-grade,
// absmax 1.0), A-frags register-resident across all 19 steps.

#define TT 8
#define PLEN 12
#define ROWS 64
#define NBLK 256
#define NTHR 512
#define TPB 8          // tiles/block: B=131072 -> 2048 tiles / 256 blocks
#define NBUCK 16
#define XSTR 112       // halves per X row (96 used)
#define CSTR 66        // hstF/hstP row stride (floats)
#define ASTR 68        // aval stride

typedef unsigned short u16;
typedef short short8 __attribute__((ext_vector_type(8)));
typedef float f4 __attribute__((ext_vector_type(4)));

// stats layout (doubles):
#define ST_ENCM 0                              // [NBUCK][8]  obs moments
#define ST_HP(d)  (128 + (d)*512)              // [NBUCK][32] d=0..11
#define ST_MOM(d) (128 + PLEN*512 + (d)*128)   // [NBUCK][8]  lastpos moments
#define ST_TOTAL  (128 + PLEN*512 + PLEN*128)  // 7808

struct KP {
  const float *obs;
  const float *seW1,*seb1,*seg,*sebeta,*seW2,*seb2;
  const float *hpW1,*hpb1,*hpg,*hpbeta,*hpW2,*hpb2;
  const float *Wih,*Whh,*bih,*bhh;
  const int *xmax,*ymax;
  float *h,*c,*lastpos,*M,*gbias,*gbc;
  u16 *W1G,*W2G,*W3G;
  double *stats;
  float *out;
  int B;
};

__device__ __forceinline__ float finv(float d){
  float r = __builtin_amdgcn_rcpf(d);
  return r*(2.f - d*r);
}
__device__ __forceinline__ float sigf(float x){
  float z = fminf(fmaxf(-x, -80.f), 80.f);
  return finv(1.f + __expf(z));
}
__device__ __forceinline__ float tanhf_(float x){
  float z = fminf(fmaxf(2.f*x, -80.f), 80.f);
  return 1.f - 2.f*finv(__expf(z) + 1.f);
}
__device__ __forceinline__ u16 f2bf(float x){
  union{float f; unsigned u;} v; v.f = x;
  unsigned r = v.u + 0x7FFFu + ((v.u >> 16) & 1u);
  return (u16)(r >> 16);
}
__device__ __forceinline__ float bf2f(u16 b){
  union{unsigned u; float f;} v; v.u = ((unsigned)b) << 16; return v.f;
}
__device__ __forceinline__ void split3(float x, u16& a, u16& b, u16& c){
  a = f2bf(x);
  float r1 = x - bf2f(a);
  b = f2bf(r1);
  float r2 = r1 - bf2f(b);
  c = f2bf(r2);
}
__device__ __forceinline__ double aload(const double* p){
  return __hip_atomic_load(p, __ATOMIC_RELAXED, __HIP_MEMORY_SCOPE_AGENT);
}

// MFMA gate GEMM (R8-verified): acc[ci][rt] over K=96, 6-product 3-way split.
__device__ __forceinline__ void gemm_gates(const u16* __restrict__ X1,
                                           const u16* __restrict__ X2,
                                           const u16* __restrict__ X3,
                                           const short8 (&A1)[2][3],
                                           const short8 (&A2)[2][3],
                                           const short8 (&A3)[2][3],
                                           const f4 (&bias)[2],
                                           f4 (&acc)[2][4], int lane){
  const int c = lane & 15, q = lane >> 4;
  #pragma unroll
  for (int ci = 0; ci < 2; ++ci)
    #pragma unroll
    for (int rt = 0; rt < 4; ++rt) acc[ci][rt] = bias[ci];
  #pragma unroll
  for (int rt = 0; rt < 4; ++rt){
    #pragma unroll
    for (int kc = 0; kc < 3; ++kc){
      const int off = (rt*16 + c)*XSTR + kc*32 + q*8;
      short8 b1 = *(const short8*)&X1[off];
      short8 b2 = *(const short8*)&X2[off];
      short8 b3 = *(const short8*)&X3[off];
      #pragma unroll
      for (int ci = 0; ci < 2; ++ci){
        acc[ci][rt] = __builtin_amdgcn_mfma_f32_16x16x32_bf16(A1[ci][kc], b1, acc[ci][rt], 0, 0, 0);
        acc[ci][rt] = __builtin_amdgcn_mfma_f32_16x16x32_bf16(A1[ci][kc], b2, acc[ci][rt], 0, 0, 0);
        acc[ci][rt] = __builtin_amdgcn_mfma_f32_16x16x32_bf16(A2[ci][kc], b1, acc[ci][rt], 0, 0, 0);
        acc[ci][rt] = __builtin_amdgcn_mfma_f32_16x16x32_bf16(A2[ci][kc], b2, acc[ci][rt], 0, 0, 0);
        acc[ci][rt] = __builtin_amdgcn_mfma_f32_16x16x32_bf16(A1[ci][kc], b3, acc[ci][rt], 0, 0, 0);
        acc[ci][rt] = __builtin_amdgcn_mfma_f32_16x16x32_bf16(A3[ci][kc], b1, acc[ci][rt], 0, 0, 0);
      }
    }
  }
}

// Epilogue: lane's acc = gates i,f,g,o of (j=(2wid+ci)*4+q, r=rt*16+c).
__device__ __forceinline__ void do_epilogue(f4 (&acc)[2][4], float (&cr)[2][4],
                                            u16* X1, u16* X2, u16* X3, float* hstF,
                                            bool first, bool wX, bool wH,
                                            int lane, int wid){
  const int c = lane & 15, q = lane >> 4;
  #pragma unroll
  for (int ci = 0; ci < 2; ++ci){
    const int j = (2*wid + ci)*4 + q;
    #pragma unroll
    for (int rt = 0; rt < 4; ++rt){
      const int r = rt*16 + c;
      float iv = acc[ci][rt].x, fv = acc[ci][rt].y;
      float gv = acc[ci][rt].z, ov = acc[ci][rt].w;
      float cp = first ? 0.f : cr[ci][rt];
      float cn = sigf(fv)*cp + sigf(iv)*tanhf_(gv);
      cr[ci][rt] = cn;
      float hn = sigf(ov)*tanhf_(cn);
      if (wX){
        u16 a, b, cc2;
        split3(hn, a, b, cc2);
        X1[r*XSTR + j] = a; X2[r*XSTR + j] = b; X3[r*XSTR + j] = cc2;
      }
      if (wH) hstF[j*CSTR + r] = hn;
    }
  }
}

__device__ __forceinline__ void stage_v_row(const float* sef, u16* X1, u16* X2, u16* X3,
                                            float p0, float p1, int r){
  #pragma unroll
  for (int q = 0; q < 16; ++q){
    float tv = sef[q]*p0 + sef[16+q]*p1 + sef[32+q];
    tv = tv > 0.f ? tv : 0.f;
    u16 a, b, c;
    split3(tv, a, b, c);
    X1[r*XSTR + 64 + q] = a;
    X2[r*XSTR + 64 + q] = b;
    X3[r*XSTR + 64 + q] = c;
  }
}

__device__ __forceinline__ void aval_cells(const KP& P, const float* __restrict__ hstF,
                                           float* __restrict__ aval, int tid){
  #pragma unroll
  for (int cc = 0; cc < 2; ++cc){
    const int idx = cc*512 + tid;
    const int q = idx >> 6, r = idx & 63;
    float a = P.hpb1[q];
    #pragma unroll 8
    for (int k = 0; k < 64; ++k) a += hstF[k*CSTR + r]*P.hpW1[q*64 + k];
    aval[q*ASTR + r] = a;
  }
}

__device__ __forceinline__ void bucket_reduce_aval(const float* __restrict__ aval,
                                                   double* st, int tid, int tile){
  if (tid < 16){
    double s = 0.0, s2 = 0.0;
    for (int r = 0; r < ROWS; ++r){
      double v = (double)aval[tid*ASTR + r];
      s += v; s2 += v*v;
    }
    double* b = st + (tile & (NBUCK-1))*32;
    atomicAdd(&b[tid], s);
    atomicAdd(&b[16+tid], s2);
  }
}

// se fold from 5 moments (f64 exact): t = a*x + b*y + c per channel.
__device__ __forceinline__ void fold_se_mom(const KP& P, const double* stb, double N,
                                            float* sef, int tid){
  if (tid < 16){
    double Sx=0, Sy=0, Sxx=0, Syy=0, Sxy=0;
    for (int b = 0; b < NBUCK; ++b){
      const double* m = stb + b*8;
      Sx += aload(m); Sy += aload(m+1); Sxx += aload(m+2);
      Syy += aload(m+3); Sxy += aload(m+4);
    }
    double a = (double)P.seW1[2*tid], bb = (double)P.seW1[2*tid+1], cb = (double)P.seb1[tid];
    double S1 = a*Sx + bb*Sy + N*cb;
    double S2 = a*a*Sxx + bb*bb*Syy + 2.0*a*bb*Sxy + 2.0*a*cb*Sx + 2.0*bb*cb*Sy + N*cb*cb;
    double mu = S1/N, var = S2/N - mu*mu;
    float sc = rsqrtf((float)var + 1e-5f) * P.seg[tid];
    float sh = P.sebeta[tid] - (float)mu*sc;
    sef[tid]      = P.seW1[2*tid]*sc;
    sef[16 + tid] = P.seW1[2*tid+1]*sc;
    sef[32 + tid] = P.seb1[tid]*sc + sh;
  }
}

__global__ __launch_bounds__(NTHR) void k_all(KP P){
  __shared__ __align__(16) char LB[43008 + 16896 + 4352];
  u16*   X1   = (u16*)LB;
  u16*   X2   = X1 + 7168;
  u16*   X3   = X2 + 7168;
  float* hstF = (float*)(LB + 43008);
  float* aval = (float*)(LB + 43008 + 16896);
  float* hstP = (float*)LB;        // pos-phase alias (16896 <= 43008)
  float* vt   = hstF;              // pos-phase alias (4352 <= 16896)
  __shared__ float sef[48];
  __shared__ float hpf[32];
  __shared__ double redd[5*9];

  cg::grid_group grid = cg::this_grid();
  const int tid = threadIdx.x, lane = tid & 63, wid = tid >> 6, blk = blockIdx.x;
  const int B = P.B;
  const float xm = (float)P.xmax[0], ym = (float)P.ymax[0];

  // ---------- Phase 0: prep (block 0) + stats zero (block 1) ----------
  if (blk == 0){
    if (tid < 256){
      const int g = tid;
      const float* wr = P.Wih + g*64;
      double gb = (double)P.bih[g] + (double)P.bhh[g];
      for (int e = 0; e < 64; ++e) gb += (double)wr[e]*(double)P.seb2[e];
      P.gbias[g] = (float)gb;
      for (int q = 0; q < 16; ++q){
        double m = 0.0;
        for (int e = 0; e < 64; ++e) m += (double)wr[e]*(double)P.seW2[e*16+q];
        P.M[g*16+q] = (float)m;
      }
    }
    __syncthreads();
    if (tid < 256){
      const int cidx = tid, gate = cidx & 3, j = cidx >> 2;
      P.gbc[cidx] = P.gbias[gate*64 + j];
      for (int k = 0; k < 96; ++k){
        float w = 0.f;
        if (k < 64)      w = P.Whh[(gate*64 + j)*64 + k];
        else if (k < 80) w = P.M[(gate*64 + j)*16 + (k - 64)];
        u16 a, b, c;
        split3(w, a, b, c);
        P.W1G[cidx*96 + k] = a;
        P.W2G[cidx*96 + k] = b;
        P.W3G[cidx*96 + k] = c;
      }
    }
  } else if (blk == 1){
    for (int i = tid; i < ST_TOTAL; i += NTHR) P.stats[i] = 0.0;
  }
  grid.sync();

  // ---------- Phase 1: encode-embedding moments over T*B ----------
  {
    const int row = blk*NTHR + tid;            // NBLK*NTHR == B
    double sx=0, sy=0, sxx=0, syy=0, sxy=0;
    #pragma unroll 1
    for (int t = 0; t < TT; ++t){
      float2 o = ((const float2*)P.obs)[(long)t*B + row];
      float x = o.x/xm, y = o.y/ym;
      sx += (double)x; sy += (double)y;
      sxx += (double)x*(double)x; syy += (double)y*(double)y;
      sxy += (double)x*(double)y;
    }
    #pragma unroll
    for (int off = 32; off; off >>= 1){
      sx  += __shfl_down(sx,  off, 64);
      sy  += __shfl_down(sy,  off, 64);
      sxx += __shfl_down(sxx, off, 64);
      syy += __shfl_down(syy, off, 64);
      sxy += __shfl_down(sxy, off, 64);
    }
    if (lane == 0){
      redd[0*9+wid]=sx; redd[1*9+wid]=sy; redd[2*9+wid]=sxx;
      redd[3*9+wid]=syy; redd[4*9+wid]=sxy;
    }
    __syncthreads();
    if (tid < 5){
      double s = 0.0;
      for (int w = 0; w < 8; ++w) s += redd[tid*9 + w];
      atomicAdd(&P.stats[ST_ENCM + (blk & (NBUCK-1))*8 + tid], s);
    }
    __syncthreads();
  }
  grid.sync();

  // ---------- A-fragments (register-resident for the rest of the kernel) ----------
  short8 A1[2][3], A2[2][3], A3[2][3];
  f4 bias[2];
  {
    const int c = lane & 15, q = lane >> 4;
    #pragma unroll
    for (int ci = 0; ci < 2; ++ci){
      const int crow = (2*wid + ci)*16 + c;
      #pragma unroll
      for (int kc = 0; kc < 3; ++kc){
        A1[ci][kc] = *(const short8*)&P.W1G[crow*96 + kc*32 + q*8];
        A2[ci][kc] = *(const short8*)&P.W2G[crow*96 + kc*32 + q*8];
        A3[ci][kc] = *(const short8*)&P.W3G[crow*96 + kc*32 + q*8];
      }
      bias[ci] = *(const f4*)&P.gbc[(2*wid + ci)*16 + q*4];
    }
  }

  // ---------- Phase 2: encode (8 steps per tile; c in regs per tile) ----------
  fold_se_mom(P, P.stats + ST_ENCM, 8.0*(double)B, sef, tid);
  __syncthreads();

  #pragma unroll 1
  for (int ti = 0; ti < TPB; ++ti){
    const long row0 = ((long)blk*TPB + ti)*ROWS;
    for (int m = tid; m < 10752; m += NTHR) ((unsigned*)LB)[m] = 0u;  // zero X planes
    __syncthreads();
    if (tid < ROWS){
      float2 o = ((const float2*)P.obs)[row0 + tid];
      stage_v_row(sef, X1, X2, X3, o.x/xm, o.y/ym, tid);
    }
    __syncthreads();

    float cr[2][4];
    f4 acc[2][4];
    #pragma unroll 1
    for (int t = 0; t < TT; ++t){
      gemm_gates(X1, X2, X3, A1, A2, A3, bias, acc, lane);
      __syncthreads();
      do_epilogue(acc, cr, X1, X2, X3, hstF, t == 0, true, t == TT-1, lane, wid);
      if (t < TT-1 && tid < ROWS){
        float2 o = ((const float2*)P.obs)[(long)(t+1)*B + row0 + tid];
        stage_v_row(sef, X1, X2, X3, o.x/xm, o.y/ym, tid);
      }
      __syncthreads();
    }
    // write h (coalesced) and c (lane-owned) to global
    for (int m = tid; m < 64*ROWS; m += NTHR){
      int k = m >> 6, r = m & 63;
      P.h[(long)k*B + row0 + r] = hstF[k*CSTR + r];
    }
    {
      const int c2 = lane & 15, q = lane >> 4;
      #pragma unroll
      for (int ci = 0; ci < 2; ++ci){
        const int j = (2*wid + ci)*4 + q;
        #pragma unroll
        for (int rt = 0; rt < 4; ++rt)
          P.c[(long)j*B + row0 + rt*16 + c2] = cr[ci][rt];
      }
    }
    aval_cells(P, hstF, aval, tid);
    __syncthreads();
    bucket_reduce_aval(aval, P.stats + ST_HP(0), tid, blk*TPB + ti);
    __syncthreads();
  }
  grid.sync();

  // ---------- Phase 3: decode ----------
  #pragma unroll 1
  for (int d = 0; d < PLEN; ++d){
    // ---- pos: hidden2pos head + out + lastpos moments ----
    if (tid < 16){
      const double* st = P.stats + ST_HP(d);
      double s = 0.0, s2 = 0.0;
      for (int b = 0; b < NBUCK; ++b){ s += aload(&st[b*32 + tid]); s2 += aload(&st[b*32 + 16 + tid]); }
      double invN = 1.0/(double)B;
      double mu = s*invN, var = s2*invN - mu*mu;
      float sc = rsqrtf((float)var + 1e-5f) * P.hpg[tid];
      hpf[tid] = sc;
      hpf[16+tid] = P.hpbeta[tid] - (float)mu*sc;
    }
    __syncthreads();

    #pragma unroll 1
    for (int ti = 0; ti < TPB; ++ti){
      const long row0 = ((long)blk*TPB + ti)*ROWS;
      for (int m = tid; m < 64*ROWS; m += NTHR){
        int k = m >> 6, r = m & 63;
        hstP[k*CSTR + r] = P.h[(long)k*B + row0 + r];
      }
      __syncthreads();
      if (tid < 256){
        const int q = tid >> 4;
        const int rb2 = (tid & 15)*4;
        float b = P.hpb1[q];
        float4 a = make_float4(b, b, b, b);
        #pragma unroll 4
        for (int k = 0; k < 64; ++k){
          const float4 hv = *(const float4*)&hstP[k*CSTR + rb2];
          const float w = P.hpW1[q*64 + k];
          a.x += hv.x*w; a.y += hv.y*w; a.z += hv.z*w; a.w += hv.w*w;
        }
        const float sc = hpf[q], sh = hpf[16+q];
        a.x = a.x*sc + sh; a.y = a.y*sc + sh; a.z = a.z*sc + sh; a.w = a.w*sc + sh;
        a.x = a.x > 0.f ? a.x : 0.f;  a.y = a.y > 0.f ? a.y : 0.f;
        a.z = a.z > 0.f ? a.z : 0.f;  a.w = a.w > 0.f ? a.w : 0.f;
        *(float4*)&vt[q*ASTR + rb2] = a;
      }
      __syncthreads();
      if (tid < ROWS){
        float r0v = P.hpb2[0], r1v = P.hpb2[1];
        #pragma unroll
        for (int q = 0; q < 16; ++q){
          float v = vt[q*ASTR + tid];
          r0v += v*P.hpW2[q]; r1v += v*P.hpW2[16+q];
        }
        float l0, l1;
        if (d == 0){
          float2 o = ((const float2*)P.obs)[(long)(TT-1)*B + row0 + tid];
          l0 = o.x/xm; l1 = o.y/ym;
        } else {
          float2 lp = ((const float2*)P.lastpos)[row0 + tid];
          l0 = lp.x; l1 = lp.y;
        }
        l0 = sigf(r0v + l0);
        l1 = sigf(r1v + l1);
        ((float2*)P.lastpos)[row0 + tid] = make_float2(l0, l1);
        ((float2*)P.out)[(long)d*B + row0 + tid] = make_float2(l0*xm, l1*ym);
        // lastpos moments (wave 0 == tid<64)
        double a0=l0, a1=l1, a2=(double)l0*(double)l0, a3=(double)l1*(double)l1, a4=(double)l0*(double)l1;
        #pragma unroll
        for (int off = 32; off; off >>= 1){
          a0 += __shfl_down(a0, off, 64); a1 += __shfl_down(a1, off, 64);
          a2 += __shfl_down(a2, off, 64); a3 += __shfl_down(a3, off, 64);
          a4 += __shfl_down(a4, off, 64);
        }
        if (lane == 0){
          double* mm = P.stats + ST_MOM(d) + (((blk*TPB + ti) & (NBUCK-1)))*8;
          atomicAdd(&mm[0], a0); atomicAdd(&mm[1], a1); atomicAdd(&mm[2], a2);
          atomicAdd(&mm[3], a3); atomicAdd(&mm[4], a4);
        }
      }
      __syncthreads();
    }
    if (d == PLEN-1) break;           // final LSTM's outputs are unused
    grid.sync();

    // ---- lstm step d ----
    fold_se_mom(P, P.stats + ST_MOM(d), (double)B, sef, tid);
    __syncthreads();

    #pragma unroll 1
    for (int ti = 0; ti < TPB; ++ti){
      const long row0 = ((long)blk*TPB + ti)*ROWS;
      for (int m = tid; m < 64*ROWS; m += NTHR){
        int k = m >> 6, r = m & 63;
        float hv = P.h[(long)k*B + row0 + r];
        u16 a, b, cc;
        split3(hv, a, b, cc);
        X1[r*XSTR + k] = a; X2[r*XSTR + k] = b; X3[r*XSTR + k] = cc;
      }
      for (int m = tid; m < 64*16; m += NTHR){
        int r = m >> 4, k = 80 + (m & 15);
        X1[r*XSTR + k] = 0; X2[r*XSTR + k] = 0; X3[r*XSTR + k] = 0;
      }
      if (tid < ROWS){
        float2 lp = ((const float2*)P.lastpos)[row0 + tid];
        stage_v_row(sef, X1, X2, X3, lp.x, lp.y, tid);
      }
      // prefetch this lane's c cells (latency hidden by the gemm)
      float cr[2][4];
      {
        const int c2 = lane & 15, q = lane >> 4;
        #pragma unroll
        for (int ci = 0; ci < 2; ++ci){
          const int j = (2*wid + ci)*4 + q;
          #pragma unroll
          for (int rt = 0; rt < 4; ++rt)
            cr[ci][rt] = P.c[(long)j*B + row0 + rt*16 + c2];
        }
      }
      __syncthreads();
      f4 acc[2][4];
      gemm_gates(X1, X2, X3, A1, A2, A3, bias, acc, lane);
      __syncthreads();
      do_epilogue(acc, cr, X1, X2, X3, hstF, false, false, true, lane, wid);
      {
        const int c2 = lane & 15, q = lane >> 4;
        #pragma unroll
        for (int ci = 0; ci < 2; ++ci){
          const int j = (2*wid + ci)*4 + q;
          #pragma unroll
          for (int rt = 0; rt < 4; ++rt)
            P.c[(long)j*B + row0 + rt*16 + c2] = cr[ci][rt];
        }
      }
      __syncthreads();
      for (int m = tid; m < 64*ROWS; m += NTHR){
        int k = m >> 6, r = m & 63;
        P.h[(long)k*B + row0 + r] = hstF[k*CSTR + r];
      }
      aval_cells(P, hstF, aval, tid);
      __syncthreads();
      bucket_reduce_aval(aval, P.stats + ST_HP(d+1), tid, blk*TPB + ti);
      __syncthreads();
    }
    grid.sync();
  }
}

extern "C" void kernel_launch(void* const* d_in, const int* in_sizes, int n_in,
                              void* d_out, int out_size, void* d_ws, size_t ws_size,
                              hipStream_t stream){
  KP P;
  P.obs    = (const float*)d_in[0];
  P.seW1   = (const float*)d_in[1];
  P.seb1   = (const float*)d_in[2];
  P.seg    = (const float*)d_in[3];
  P.sebeta = (const float*)d_in[4];
  P.seW2   = (const float*)d_in[5];
  P.seb2   = (const float*)d_in[6];
  P.hpW1   = (const float*)d_in[7];
  P.hpb1   = (const float*)d_in[8];
  P.hpg    = (const float*)d_in[9];
  P.hpbeta = (const float*)d_in[10];
  P.hpW2   = (const float*)d_in[11];
  P.hpb2   = (const float*)d_in[12];
  P.Wih    = (const float*)d_in[13];
  P.Whh    = (const float*)d_in[14];
  P.bih    = (const float*)d_in[15];
  P.bhh    = (const float*)d_in[16];
  P.xmax   = (const int*)d_in[17];
  P.ymax   = (const int*)d_in[18];
  // d_in[19] = pred_len (fixed 12; baked into the phase loop)

  const int B = in_sizes[0] / (TT*2);   // 131072
  P.B = B;
  float* ws = (float*)d_ws;
  size_t o = (size_t)130*B;
  P.h       = ws;                        // [64][B]
  P.c       = ws + (size_t)64*B;         // [64][B]
  P.lastpos = ws + (size_t)128*B;        // [B][2]
  P.M       = ws + o;                    // [256][16]
  P.gbias   = ws + o + 4096;             // [256]
  P.gbc     = ws + o + 4352;             // [256]
  P.W1G     = (u16*)(ws + o + 4608);     // [256][96] u16 = 49152 B
  P.W2G     = (u16*)(ws + o + 4608 + 12288);
  P.W3G     = (u16*)(ws + o + 4608 + 24576);
  P.stats   = (double*)(ws + o + 4608 + 36864);  // 7808 doubles
  P.out     = (float*)d_out;

  void* kargs[] = { (void*)&P };
  hipLaunchCooperativeKernel(k_all, dim3(NBLK), dim3(NTHR), kargs, 0, stream);
}

// Round 11
// 1937.727 us; speedup vs baseline: 1.5485x; 1.5485x over previous
//
#include <hip/hip_runtime.h>
#include <math.h>

// TrajectoryLSTM — R11: R10's design with the ws-allocation bug FIXED.
// R10 failed (absmax 74.875) because W1G/W2G/W3G were spaced 3072 float-slots
// apart but each needs 256*96 u16 = 12288 float-slots -> k_prep2's writes
// clobbered the weight splits (garbage-but-sigmoid-bounded outputs). H planes
// had the same overlap (need 512 slots, given 256). Offsets corrected; design
// unchanged:
//  * h stored ONLY as 3 split-bf16 global planes Xg1/2/3[B][64] (MFMA B-frag
//    layout); decode lstm loads B-frags DIRECT from global. v16 in-lane from
//    lastpos. c = per-lane registers <-> global (R9-verified).
//  * lstm tail persists aval = hpW1@h+b (MFMA, 3-way split) as avalg[16][B];
//    pos is a thin elementwise kernel.
//  * obs/lastpos BN via 5-moment f64 scheme (R9-verified); hp stats via
//    width-16 f64 shuffles + bucketed atomics.
// Carried (verified): 3-way/6-product split-bf16 MFMA gates (absmax 0.5-1.0),
// M=Wih@seW2 fold, c'=4j+gate interleave, fast sigf/tanh. pred_len fixed 12.

#define TT 8
#define PLEN 12
#define ROWS 64
#define NBUCK 16
#define XSTR 112   // LDS transpose-plane row stride (u16)

typedef unsigned short u16;
typedef short short8 __attribute__((ext_vector_type(8)));
typedef float f4 __attribute__((ext_vector_type(4)));
union U8 { u16 u[8]; short8 v; };

// stats layout (doubles)
#define ST_ENCM 0                              // [NBUCK][8]  obs moments
#define ST_HP(d)  (128 + (d)*512)              // [NBUCK][32]
#define ST_MOM(d) (128 + PLEN*512 + (d)*128)   // [NBUCK][8]  lastpos moments
#define ST_TOTAL  (128 + PLEN*512 + PLEN*128)  // 7808

struct KP {
  const float *obs;
  const float *seW1,*seb1,*seg,*sebeta,*seW2,*seb2;
  const float *hpW1,*hpb1,*hpg,*hpbeta,*hpW2,*hpb2;
  const float *Wih,*Whh,*bih,*bhh;
  const int *xmax,*ymax;
  float *c,*lastpos,*avalg,*M,*gbias,*gbc;
  u16 *Xg1,*Xg2,*Xg3,*W1G,*W2G,*W3G,*H1G,*H2G,*H3G;
  double *stats;
  float *out;
  int B;
};

__device__ __forceinline__ float finv(float d){
  float r = __builtin_amdgcn_rcpf(d);
  return r*(2.f - d*r);
}
__device__ __forceinline__ float sigf(float x){
  float z = fminf(fmaxf(-x, -80.f), 80.f);
  return finv(1.f + __expf(z));
}
__device__ __forceinline__ float tanhf_(float x){
  float z = fminf(fmaxf(2.f*x, -80.f), 80.f);
  return 1.f - 2.f*finv(__expf(z) + 1.f);
}
__device__ __forceinline__ u16 f2bf(float x){
  union{float f; unsigned u;} v; v.f = x;
  unsigned r = v.u + 0x7FFFu + ((v.u >> 16) & 1u);
  return (u16)(r >> 16);
}
__device__ __forceinline__ float bf2f(u16 b){
  union{unsigned u; float f;} v; v.u = ((unsigned)b) << 16; return v.f;
}
__device__ __forceinline__ void split3(float x, u16& a, u16& b, u16& c){
  a = f2bf(x);
  float r1 = x - bf2f(a);
  b = f2bf(r1);
  float r2 = r1 - bf2f(b);
  c = f2bf(r2);
}

// 6-product triple for one (A,B) k-chunk pair
#define MF6(A1c,A2c,A3c,b1,b2,b3,accv) \
  accv = __builtin_amdgcn_mfma_f32_16x16x32_bf16(A1c, b1, accv, 0,0,0); \
  accv = __builtin_amdgcn_mfma_f32_16x16x32_bf16(A1c, b2, accv, 0,0,0); \
  accv = __builtin_amdgcn_mfma_f32_16x16x32_bf16(A2c, b1, accv, 0,0,0); \
  accv = __builtin_amdgcn_mfma_f32_16x16x32_bf16(A2c, b2, accv, 0,0,0); \
  accv = __builtin_amdgcn_mfma_f32_16x16x32_bf16(A1c, b3, accv, 0,0,0); \
  accv = __builtin_amdgcn_mfma_f32_16x16x32_bf16(A3c, b1, accv, 0,0,0);

// se fold from 5 lastpos/obs moments (f64 exact): t = a*x + b*y + cb.
__device__ __forceinline__ void fold_se_mom(const KP& P, const double* stb, double N,
                                            float* sef, int tid){
  if (tid < 16){
    double Sx=0, Sy=0, Sxx=0, Syy=0, Sxy=0;
    for (int b = 0; b < NBUCK; ++b){
      const double* m = stb + b*8;
      Sx += m[0]; Sy += m[1]; Sxx += m[2]; Syy += m[3]; Sxy += m[4];
    }
    double a = (double)P.seW1[2*tid], bb = (double)P.seW1[2*tid+1], cb = (double)P.seb1[tid];
    double S1 = a*Sx + bb*Sy + N*cb;
    double S2 = a*a*Sxx + bb*bb*Syy + 2.0*a*bb*Sxy + 2.0*a*cb*Sx + 2.0*bb*cb*Sy + N*cb*cb;
    double mu = S1/N, var = S2/N - mu*mu;
    float sc = rsqrtf((float)var + 1e-5f) * P.seg[tid];
    float sh = P.sebeta[tid] - (float)mu*sc;
    sef[tid]      = P.seW1[2*tid]*sc;
    sef[16 + tid] = P.seW1[2*tid+1]*sc;
    sef[32 + tid] = P.seb1[tid]*sc + sh;
  }
}

// Epilogue: lane's acc = gates i,f,g,o of (j=(2wid+ci)*4+q, r=rt*16+c).
// Writes new h (split3) into LDS transpose planes; updates per-lane c regs.
__device__ __forceinline__ void do_epilogue(f4 (&acc)[2][4], float (&cr)[2][4],
                                            u16* X1, u16* X2, u16* X3,
                                            bool first, int lane, int wid){
  const int c = lane & 15, q = lane >> 4;
  #pragma unroll
  for (int ci = 0; ci < 2; ++ci){
    const int j = (2*wid + ci)*4 + q;
    #pragma unroll
    for (int rt = 0; rt < 4; ++rt){
      const int r = rt*16 + c;
      float iv = acc[ci][rt].x, fv = acc[ci][rt].y;
      float gv = acc[ci][rt].z, ov = acc[ci][rt].w;
      float cp = first ? 0.f : cr[ci][rt];
      float cn = sigf(fv)*cp + sigf(iv)*tanhf_(gv);
      cr[ci][rt] = cn;
      float hn = sigf(ov)*tanhf_(cn);
      u16 a, b, cc2;
      split3(hn, a, b, cc2);
      X1[r*XSTR + j] = a; X2[r*XSTR + j] = b; X3[r*XSTR + j] = cc2;
    }
  }
}

// Post-step tail: copy LDS planes -> global Xg (coalesced), aval MFMA from LDS
// planes (waves 0..3, rt=wid), write avalg, hp stats -> f64 atomics.
__device__ __forceinline__ void tail_xg_aval(const KP& P, long row0,
                                             const u16* X1, const u16* X2, const u16* X3,
                                             double* redd, double* st,
                                             int tid, int lane, int wid, int blk){
  {
    int r = tid >> 3, ch = tid & 7;
    *(short8*)&P.Xg1[(row0 + r)*64 + ch*8] = *(const short8*)&X1[r*XSTR + ch*8];
    *(short8*)&P.Xg2[(row0 + r)*64 + ch*8] = *(const short8*)&X2[r*XSTR + ch*8];
    *(short8*)&P.Xg3[(row0 + r)*64 + ch*8] = *(const short8*)&X3[r*XSTR + ch*8];
  }
  if (wid < 4){
    const int c = lane & 15, q = lane >> 4, rt = wid;
    f4 av = *(const f4*)&P.hpb1[q*4];
    #pragma unroll
    for (int kc = 0; kc < 2; ++kc){
      const int aoff = (lane & 15)*64 + kc*32 + q*8;
      short8 HA1 = *(const short8*)&P.H1G[aoff];
      short8 HA2 = *(const short8*)&P.H2G[aoff];
      short8 HA3 = *(const short8*)&P.H3G[aoff];
      const int boff = (rt*16 + c)*XSTR + kc*32 + q*8;
      short8 b1 = *(const short8*)&X1[boff];
      short8 b2 = *(const short8*)&X2[boff];
      short8 b3 = *(const short8*)&X3[boff];
      MF6(HA1, HA2, HA3, b1, b2, b3, av);
    }
    #pragma unroll
    for (int i = 0; i < 4; ++i)
      P.avalg[(long)(q*4 + i)*P.B + row0 + rt*16 + c] = av[i];
    #pragma unroll
    for (int i = 0; i < 4; ++i){
      double s = (double)av[i];
      double s2 = s*s;
      #pragma unroll
      for (int off = 8; off; off >>= 1){
        s  += __shfl_down(s,  off, 16);
        s2 += __shfl_down(s2, off, 16);
      }
      if (c == 0){
        redd[wid*32 + q*4 + i]      = s;
        redd[wid*32 + 16 + q*4 + i] = s2;
      }
    }
  }
  __syncthreads();
  if (tid < 32){
    double s = redd[tid] + redd[32 + tid] + redd[64 + tid] + redd[96 + tid];
    atomicAdd(&st[(blk & (NBUCK-1))*32 + tid], s);
  }
}

// --- k_prep: M = Wih@seW2, gbias = Wih@seb2 + bih + bhh ---
__global__ __launch_bounds__(256) void k_prep(KP P){
  const int g = threadIdx.x;
  const float* __restrict__ wr = P.Wih + g*64;
  double gb = (double)P.bih[g] + (double)P.bhh[g];
  for (int e = 0; e < 64; ++e) gb += (double)wr[e]*(double)P.seb2[e];
  P.gbias[g] = (float)gb;
  for (int q = 0; q < 16; ++q){
    double m = 0.0;
    for (int e = 0; e < 64; ++e) m += (double)wr[e]*(double)P.seW2[e*16+q];
    P.M[g*16+q] = (float)m;
  }
}

// --- k_prep2: 3-way splits of gate weights (A-layout) + gbc + hpW1 splits ---
__global__ __launch_bounds__(256) void k_prep2(KP P){
  const int cidx = threadIdx.x;
  const int gate = cidx & 3, j = cidx >> 2;
  P.gbc[cidx] = P.gbias[gate*64 + j];
  for (int k = 0; k < 96; ++k){
    float w = 0.f;
    if (k < 64)      w = P.Whh[(gate*64 + j)*64 + k];
    else if (k < 80) w = P.M[(gate*64 + j)*16 + (k - 64)];
    u16 a, b, c;
    split3(w, a, b, c);
    P.W1G[cidx*96 + k] = a;
    P.W2G[cidx*96 + k] = b;
    P.W3G[cidx*96 + k] = c;
  }
  if (cidx < 16){
    for (int k = 0; k < 64; ++k){
      u16 a, b, c;
      split3(P.hpW1[cidx*64 + k], a, b, c);
      P.H1G[cidx*64 + k] = a;
      P.H2G[cidx*64 + k] = b;
      P.H3G[cidx*64 + k] = c;
    }
  }
}

// --- obs 5-moment stats over T*B (R9-verified) ---
__global__ __launch_bounds__(512) void k_stats_mom(KP P){
  __shared__ double redd[5*9];
  const int tid = threadIdx.x, lane = tid & 63, wid = tid >> 6;
  const int row = blockIdx.x*512 + tid;
  const int B = P.B;
  const float xm = (float)P.xmax[0], ym = (float)P.ymax[0];
  double sx=0, sy=0, sxx=0, syy=0, sxy=0;
  #pragma unroll 1
  for (int t = 0; t < TT; ++t){
    float2 o = ((const float2*)P.obs)[(long)t*B + row];
    float x = o.x/xm, y = o.y/ym;
    sx += (double)x; sy += (double)y;
    sxx += (double)x*(double)x; syy += (double)y*(double)y;
    sxy += (double)x*(double)y;
  }
  #pragma unroll
  for (int off = 32; off; off >>= 1){
    sx  += __shfl_down(sx,  off, 64);
    sy  += __shfl_down(sy,  off, 64);
    sxx += __shfl_down(sxx, off, 64);
    syy += __shfl_down(syy, off, 64);
    sxy += __shfl_down(sxy, off, 64);
  }
  if (lane == 0){
    redd[0*9+wid]=sx; redd[1*9+wid]=sy; redd[2*9+wid]=sxx;
    redd[3*9+wid]=syy; redd[4*9+wid]=sxy;
  }
  __syncthreads();
  if (tid < 5){
    double s = 0.0;
    for (int w = 0; w < 8; ++w) s += redd[tid*9 + w];
    atomicAdd(&P.stats[ST_ENCM + (blockIdx.x & (NBUCK-1))*8 + tid], s);
  }
}

// --- k_enc: 8 encode steps; X planes LDS-resident; c in regs; tail writes
//     Xg + avalg + hp stats for decode step 0. ---
__global__ __launch_bounds__(512) void k_enc(KP P){
  __shared__ __align__(16) u16 X1[ROWS*XSTR];
  __shared__ __align__(16) u16 X2[ROWS*XSTR];
  __shared__ __align__(16) u16 X3[ROWS*XSTR];
  __shared__ float sef[48];
  __shared__ double redd[128];
  const int tid = threadIdx.x, lane = tid & 63, wid = tid >> 6;
  const int B = P.B;
  const long row0 = (long)blockIdx.x * ROWS;
  const float xm = (float)P.xmax[0], ym = (float)P.ymax[0];

  for (int m = tid; m < 3584; m += 512){
    ((unsigned*)X1)[m] = 0u; ((unsigned*)X2)[m] = 0u; ((unsigned*)X3)[m] = 0u;
  }
  fold_se_mom(P, P.stats + ST_ENCM, 8.0*(double)B, sef, tid);
  __syncthreads();

  if (tid < ROWS){
    float2 o = ((const float2*)P.obs)[row0 + tid];
    float p0 = o.x/xm, p1 = o.y/ym;
    #pragma unroll
    for (int q = 0; q < 16; ++q){
      float tv = sef[q]*p0 + sef[16+q]*p1 + sef[32+q];
      tv = tv > 0.f ? tv : 0.f;
      u16 a, b, c;
      split3(tv, a, b, c);
      X1[tid*XSTR + 64 + q] = a; X2[tid*XSTR + 64 + q] = b; X3[tid*XSTR + 64 + q] = c;
    }
  }
  __syncthreads();

  const int c = lane & 15, q = lane >> 4;
  float cr[2][4];
  f4 acc[2][4];

  #pragma unroll 1
  for (int t = 0; t < TT; ++t){
    #pragma unroll
    for (int ci = 0; ci < 2; ++ci){
      f4 bias = *(const f4*)&P.gbc[(2*wid + ci)*16 + q*4];
      #pragma unroll
      for (int rt = 0; rt < 4; ++rt) acc[ci][rt] = bias;
    }
    #pragma unroll
    for (int rt = 0; rt < 4; ++rt){
      #pragma unroll
      for (int kc = 0; kc < 3; ++kc){
        const int boff = (rt*16 + c)*XSTR + kc*32 + q*8;
        short8 b1 = *(const short8*)&X1[boff];
        short8 b2 = *(const short8*)&X2[boff];
        short8 b3 = *(const short8*)&X3[boff];
        #pragma unroll
        for (int ci = 0; ci < 2; ++ci){
          const int aoff = ((2*wid + ci)*16 + c)*96 + kc*32 + q*8;
          short8 A1 = *(const short8*)&P.W1G[aoff];
          short8 A2 = *(const short8*)&P.W2G[aoff];
          short8 A3 = *(const short8*)&P.W3G[aoff];
          MF6(A1, A2, A3, b1, b2, b3, acc[ci][rt]);
        }
      }
    }
    __syncthreads();
    do_epilogue(acc, cr, X1, X2, X3, t == 0, lane, wid);
    if (t < TT-1 && tid < ROWS){
      float2 o = ((const float2*)P.obs)[(long)(t+1)*B + row0 + tid];
      float p0 = o.x/xm, p1 = o.y/ym;
      #pragma unroll
      for (int qq = 0; qq < 16; ++qq){
        float tv = sef[qq]*p0 + sef[16+qq]*p1 + sef[32+qq];
        tv = tv > 0.f ? tv : 0.f;
        u16 a, b, cc;
        split3(tv, a, b, cc);
        X1[tid*XSTR + 64 + qq] = a; X2[tid*XSTR + 64 + qq] = b; X3[tid*XSTR + 64 + qq] = cc;
      }
    }
    __syncthreads();
  }

  #pragma unroll
  for (int ci = 0; ci < 2; ++ci){
    const int j = (2*wid + ci)*4 + q;
    #pragma unroll
    for (int rt = 0; rt < 4; ++rt)
      P.c[(long)j*B + row0 + rt*16 + c] = cr[ci][rt];
  }
  tail_xg_aval(P, row0, X1, X2, X3, redd, P.stats + ST_HP(0), tid, lane, wid, blockIdx.x);
}

// --- k_dec_pos: thin elementwise head from avalg ---
template<bool FIRSTD>
__global__ __launch_bounds__(256) void k_dec_pos(KP P, int d){
  __shared__ float hpf[32];
  __shared__ double redd[5*5];
  const int tid = threadIdx.x, lane = tid & 63, wid = tid >> 6;
  const int B = P.B;
  const int row = blockIdx.x*256 + tid;
  if (tid < 16){
    const double* st = P.stats + ST_HP(d);
    double s = 0.0, s2 = 0.0;
    for (int b = 0; b < NBUCK; ++b){ s += st[b*32 + tid]; s2 += st[b*32 + 16 + tid]; }
    double invN = 1.0/(double)B;
    double mu = s*invN, var = s2*invN - mu*mu;
    float sc = rsqrtf((float)var + 1e-5f) * P.hpg[tid];
    hpf[tid] = sc;
    hpf[16+tid] = P.hpbeta[tid] - (float)mu*sc;
  }
  __syncthreads();

  float r0v = P.hpb2[0], r1v = P.hpb2[1];
  #pragma unroll
  for (int qq = 0; qq < 16; ++qq){
    float a = P.avalg[(long)qq*B + row];
    a = a*hpf[qq] + hpf[16+qq];
    a = a > 0.f ? a : 0.f;
    r0v += a*P.hpW2[qq]; r1v += a*P.hpW2[16+qq];
  }
  const float xm = (float)P.xmax[0], ym = (float)P.ymax[0];
  float l0, l1;
  if constexpr (FIRSTD){
    float2 o = ((const float2*)P.obs)[(long)(TT-1)*B + row];
    l0 = o.x/xm; l1 = o.y/ym;
  } else {
    float2 lp = ((const float2*)P.lastpos)[row];
    l0 = lp.x; l1 = lp.y;
  }
  l0 = sigf(r0v + l0);
  l1 = sigf(r1v + l1);
  ((float2*)P.lastpos)[row] = make_float2(l0, l1);
  ((float2*)P.out)[(long)d*B + row] = make_float2(l0*xm, l1*ym);

  double a0=l0, a1=l1, a2=(double)l0*(double)l0, a3=(double)l1*(double)l1, a4=(double)l0*(double)l1;
  #pragma unroll
  for (int off = 32; off; off >>= 1){
    a0 += __shfl_down(a0, off, 64); a1 += __shfl_down(a1, off, 64);
    a2 += __shfl_down(a2, off, 64); a3 += __shfl_down(a3, off, 64);
    a4 += __shfl_down(a4, off, 64);
  }
  if (lane == 0){
    redd[0*5+wid]=a0; redd[1*5+wid]=a1; redd[2*5+wid]=a2;
    redd[3*5+wid]=a3; redd[4*5+wid]=a4;
  }
  __syncthreads();
  if (tid < 5){
    double s = 0.0;
    for (int w = 0; w < 4; ++w) s += redd[tid*5 + w];
    atomicAdd(&P.stats[ST_MOM(d) + (blockIdx.x & (NBUCK-1))*8 + tid], s);
  }
}

// --- k_dec_lstm: B-frags direct from global Xg; v in-lane; c in regs ---
template<int DUMMY>
__global__ __launch_bounds__(512) void k_dec_lstm(KP P, int d){
  __shared__ __align__(16) u16 X1[ROWS*XSTR];
  __shared__ __align__(16) u16 X2[ROWS*XSTR];
  __shared__ __align__(16) u16 X3[ROWS*XSTR];
  __shared__ float sef[48];
  __shared__ double redd[128];
  const int tid = threadIdx.x, lane = tid & 63, wid = tid >> 6;
  const int B = P.B;
  const long row0 = (long)blockIdx.x * ROWS;
  const int c = lane & 15, q = lane >> 4;

  fold_se_mom(P, P.stats + ST_MOM(d), (double)B, sef, tid);
  __syncthreads();

  // in-lane v fragments for kc=2 (k=64..79 from lastpos; 80..95 zero)
  short8 vb1[4], vb2[4], vb3[4];
  {
    const short8 z = {0,0,0,0,0,0,0,0};
    #pragma unroll
    for (int rt = 0; rt < 4; ++rt){ vb1[rt] = z; vb2[rt] = z; vb3[rt] = z; }
    if (q < 2){
      #pragma unroll
      for (int rt = 0; rt < 4; ++rt){
        float2 lp = ((const float2*)P.lastpos)[row0 + rt*16 + c];
        U8 u1, u2, u3;
        #pragma unroll
        for (int j = 0; j < 8; ++j){
          const int ch = q*8 + j;
          float tv = sef[ch]*lp.x + sef[16+ch]*lp.y + sef[32+ch];
          tv = tv > 0.f ? tv : 0.f;
          split3(tv, u1.u[j], u2.u[j], u3.u[j]);
        }
        vb1[rt] = u1.v; vb2[rt] = u2.v; vb3[rt] = u3.v;
      }
    }
  }
  // prefetch c
  float cr[2][4];
  #pragma unroll
  for (int ci = 0; ci < 2; ++ci){
    const int j = (2*wid + ci)*4 + q;
    #pragma unroll
    for (int rt = 0; rt < 4; ++rt)
      cr[ci][rt] = P.c[(long)j*B + row0 + rt*16 + c];
  }

  // gate GEMM: h-part B-frags DIRECT from global planes
  f4 acc[2][4];
  #pragma unroll
  for (int ci = 0; ci < 2; ++ci){
    f4 bias = *(const f4*)&P.gbc[(2*wid + ci)*16 + q*4];
    #pragma unroll
    for (int rt = 0; rt < 4; ++rt) acc[ci][rt] = bias;
  }
  #pragma unroll
  for (int rt = 0; rt < 4; ++rt){
    const long gb = (row0 + rt*16 + c)*64;
    #pragma unroll
    for (int kc = 0; kc < 2; ++kc){
      short8 b1 = *(const short8*)&P.Xg1[gb + kc*32 + q*8];
      short8 b2 = *(const short8*)&P.Xg2[gb + kc*32 + q*8];
      short8 b3 = *(const short8*)&P.Xg3[gb + kc*32 + q*8];
      #pragma unroll
      for (int ci = 0; ci < 2; ++ci){
        const int aoff = ((2*wid + ci)*16 + c)*96 + kc*32 + q*8;
        short8 A1 = *(const short8*)&P.W1G[aoff];
        short8 A2 = *(const short8*)&P.W2G[aoff];
        short8 A3 = *(const short8*)&P.W3G[aoff];
        MF6(A1, A2, A3, b1, b2, b3, acc[ci][rt]);
      }
    }
    #pragma unroll
    for (int ci = 0; ci < 2; ++ci){
      const int aoff = ((2*wid + ci)*16 + c)*96 + 2*32 + q*8;
      short8 A1 = *(const short8*)&P.W1G[aoff];
      short8 A2 = *(const short8*)&P.W2G[aoff];
      short8 A3 = *(const short8*)&P.W3G[aoff];
      MF6(A1, A2, A3, vb1[rt], vb2[rt], vb3[rt], acc[ci][rt]);
    }
  }

  do_epilogue(acc, cr, X1, X2, X3, false, lane, wid);
  #pragma unroll
  for (int ci = 0; ci < 2; ++ci){
    const int j = (2*wid + ci)*4 + q;
    #pragma unroll
    for (int rt = 0; rt < 4; ++rt)
      P.c[(long)j*B + row0 + rt*16 + c] = cr[ci][rt];
  }
  __syncthreads();
  tail_xg_aval(P, row0, X1, X2, X3, redd, P.stats + ST_HP(d+1), tid, lane, wid, blockIdx.x);
}

extern "C" void kernel_launch(void* const* d_in, const int* in_sizes, int n_in,
                              void* d_out, int out_size, void* d_ws, size_t ws_size,
                              hipStream_t stream){
  KP P;
  P.obs    = (const float*)d_in[0];
  P.seW1   = (const float*)d_in[1];
  P.seb1   = (const float*)d_in[2];
  P.seg    = (const float*)d_in[3];
  P.sebeta = (const float*)d_in[4];
  P.seW2   = (const float*)d_in[5];
  P.seb2   = (const float*)d_in[6];
  P.hpW1   = (const float*)d_in[7];
  P.hpb1   = (const float*)d_in[8];
  P.hpg    = (const float*)d_in[9];
  P.hpbeta = (const float*)d_in[10];
  P.hpW2   = (const float*)d_in[11];
  P.hpb2   = (const float*)d_in[12];
  P.Wih    = (const float*)d_in[13];
  P.Whh    = (const float*)d_in[14];
  P.bih    = (const float*)d_in[15];
  P.bhh    = (const float*)d_in[16];
  P.xmax   = (const int*)d_in[17];
  P.ymax   = (const int*)d_in[18];
  // d_in[19] = pred_len (fixed 12)

  const int B = in_sizes[0] / (TT*2);   // 131072
  P.B = B;
  float* ws = (float*)d_ws;
  // float-slot offsets. Xg plane = B*64 u16 = 32B float-slots. ~93.6 MB total.
  P.Xg1     = (u16*)(ws);
  P.Xg2     = (u16*)(ws + (size_t)32*B);
  P.c       = ws + (size_t)64*B;                   // [64][B] f32
  P.lastpos = ws + (size_t)128*B;                  // [B][2]
  P.Xg3     = (u16*)(ws + (size_t)130*B);
  P.avalg   = ws + (size_t)162*B;                  // [16][B]
  float* tail = ws + (size_t)178*B;
  P.M     = tail;                          // 4096
  P.gbias = tail + 4096;                   // 256
  P.gbc   = tail + 4352;                   // 256
  // FIXED: each W plane = 256*96 u16 = 24576 u16 = 12288 float-slots (R10 had 3072!)
  P.W1G   = (u16*)(tail + 4608);
  P.W2G   = (u16*)(tail + 4608 + 12288);
  P.W3G   = (u16*)(tail + 4608 + 24576);
  // FIXED: each H plane = 16*64 u16 = 1024 u16 = 512 float-slots (R10 had 256!)
  P.H1G   = (u16*)(tail + 4608 + 36864);
  P.H2G   = (u16*)(tail + 4608 + 37376);
  P.H3G   = (u16*)(tail + 4608 + 37888);
  P.stats = (double*)(tail + 4608 + 38400);  // 7808 doubles
  P.out   = (float*)d_out;

  hipMemsetAsync(P.stats, 0, ST_TOTAL*sizeof(double), stream);

  k_prep     <<<1, 256, 0, stream>>>(P);
  k_prep2    <<<1, 256, 0, stream>>>(P);
  k_stats_mom<<<B/512, 512, 0, stream>>>(P);
  k_enc      <<<B/ROWS, 512, 0, stream>>>(P);

  for (int d = 0; d < PLEN; ++d){
    if (d == 0) k_dec_pos<true ><<<B/256, 256, 0, stream>>>(P, d);
    else        k_dec_pos<false><<<B/256, 256, 0, stream>>>(P, d);
    if (d < PLEN-1) k_dec_lstm<0><<<B/ROWS, 512, 0, stream>>>(P, d);
  }
}

// Round 12
// 1850.698 us; speedup vs baseline: 1.6213x; 1.0470x over previous
//
#include <hip/hip_runtime.h>
#include <math.h>

// TrajectoryLSTM — R12: R11 (verified, 1937 us, absmax 0.5) with three
// measured-cost fixes, no numeric changes:
//  1. k_enc keeps the 18 weight A-frags REGISTER-RESIDENT across the t-loop
//     (R11 reloaded 72x16B/wave/step from global; R8 with the hoist ran 420 us
//     vs R11's 455 us).
//  2. XSTR 112 -> 104: epilogue u16 writes went from ~8-way bank conflicts
//     (24c mod 32 = 4 distinct start banks; 2.0e7 SQ_LDS_BANK_CONFLICT) to
//     ~4-way (52r mod 32 = 8 starts); b128 reads stay uniform. 16B row
//     alignment preserved (104*2 = 208 = 13*16).
//  3. k_prep+k_prep2 merged (one launch); k_dec_pos at 512 threads.
// Design (R10/R11, verified): h only as 3 split-bf16 global planes Xg[B][64]
// (MFMA B-frag layout, dec lstm loads direct from global); v16 in-lane from
// lastpos; c in per-lane regs <-> global; lstm tail persists aval=hpW1@h+b
// (MFMA) -> pos is thin elementwise; obs/lastpos BN via 5-moment f64 scheme;
// 3-way/6-product split-bf16 MFMA gates (fp32-grade). pred_len fixed 12.

#define TT 8
#define PLEN 12
#define ROWS 64
#define NBUCK 16
#define XSTR 104   // LDS transpose-plane row stride (u16); 16B-aligned rows

typedef unsigned short u16;
typedef short short8 __attribute__((ext_vector_type(8)));
typedef float f4 __attribute__((ext_vector_type(4)));
union U8 { u16 u[8]; short8 v; };

// stats layout (doubles)
#define ST_ENCM 0                              // [NBUCK][8]  obs moments
#define ST_HP(d)  (128 + (d)*512)              // [NBUCK][32]
#define ST_MOM(d) (128 + PLEN*512 + (d)*128)   // [NBUCK][8]  lastpos moments
#define ST_TOTAL  (128 + PLEN*512 + PLEN*128)  // 7808

struct KP {
  const float *obs;
  const float *seW1,*seb1,*seg,*sebeta,*seW2,*seb2;
  const float *hpW1,*hpb1,*hpg,*hpbeta,*hpW2,*hpb2;
  const float *Wih,*Whh,*bih,*bhh;
  const int *xmax,*ymax;
  float *c,*lastpos,*avalg,*M,*gbias,*gbc;
  u16 *Xg1,*Xg2,*Xg3,*W1G,*W2G,*W3G,*H1G,*H2G,*H3G;
  double *stats;
  float *out;
  int B;
};

__device__ __forceinline__ float finv(float d){
  float r = __builtin_amdgcn_rcpf(d);
  return r*(2.f - d*r);
}
__device__ __forceinline__ float sigf(float x){
  float z = fminf(fmaxf(-x, -80.f), 80.f);
  return finv(1.f + __expf(z));
}
__device__ __forceinline__ float tanhf_(float x){
  float z = fminf(fmaxf(2.f*x, -80.f), 80.f);
  return 1.f - 2.f*finv(__expf(z) + 1.f);
}
__device__ __forceinline__ u16 f2bf(float x){
  union{float f; unsigned u;} v; v.f = x;
  unsigned r = v.u + 0x7FFFu + ((v.u >> 16) & 1u);
  return (u16)(r >> 16);
}
__device__ __forceinline__ float bf2f(u16 b){
  union{unsigned u; float f;} v; v.u = ((unsigned)b) << 16; return v.f;
}
__device__ __forceinline__ void split3(float x, u16& a, u16& b, u16& c){
  a = f2bf(x);
  float r1 = x - bf2f(a);
  b = f2bf(r1);
  float r2 = r1 - bf2f(b);
  c = f2bf(r2);
}

// 6-product triple for one (A,B) k-chunk pair
#define MF6(A1c,A2c,A3c,b1,b2,b3,accv) \
  accv = __builtin_amdgcn_mfma_f32_16x16x32_bf16(A1c, b1, accv, 0,0,0); \
  accv = __builtin_amdgcn_mfma_f32_16x16x32_bf16(A1c, b2, accv, 0,0,0); \
  accv = __builtin_amdgcn_mfma_f32_16x16x32_bf16(A2c, b1, accv, 0,0,0); \
  accv = __builtin_amdgcn_mfma_f32_16x16x32_bf16(A2c, b2, accv, 0,0,0); \
  accv = __builtin_amdgcn_mfma_f32_16x16x32_bf16(A1c, b3, accv, 0,0,0); \
  accv = __builtin_amdgcn_mfma_f32_16x16x32_bf16(A3c, b1, accv, 0,0,0);

// se fold from 5 lastpos/obs moments (f64 exact): t = a*x + b*y + cb.
__device__ __forceinline__ void fold_se_mom(const KP& P, const double* stb, double N,
                                            float* sef, int tid){
  if (tid < 16){
    double Sx=0, Sy=0, Sxx=0, Syy=0, Sxy=0;
    for (int b = 0; b < NBUCK; ++b){
      const double* m = stb + b*8;
      Sx += m[0]; Sy += m[1]; Sxx += m[2]; Syy += m[3]; Sxy += m[4];
    }
    double a = (double)P.seW1[2*tid], bb = (double)P.seW1[2*tid+1], cb = (double)P.seb1[tid];
    double S1 = a*Sx + bb*Sy + N*cb;
    double S2 = a*a*Sxx + bb*bb*Syy + 2.0*a*bb*Sxy + 2.0*a*cb*Sx + 2.0*bb*cb*Sy + N*cb*cb;
    double mu = S1/N, var = S2/N - mu*mu;
    float sc = rsqrtf((float)var + 1e-5f) * P.seg[tid];
    float sh = P.sebeta[tid] - (float)mu*sc;
    sef[tid]      = P.seW1[2*tid]*sc;
    sef[16 + tid] = P.seW1[2*tid+1]*sc;
    sef[32 + tid] = P.seb1[tid]*sc + sh;
  }
}

// Epilogue: lane's acc = gates i,f,g,o of (j=(2wid+ci)*4+q, r=rt*16+c).
__device__ __forceinline__ void do_epilogue(f4 (&acc)[2][4], float (&cr)[2][4],
                                            u16* X1, u16* X2, u16* X3,
                                            bool first, int lane, int wid){
  const int c = lane & 15, q = lane >> 4;
  #pragma unroll
  for (int ci = 0; ci < 2; ++ci){
    const int j = (2*wid + ci)*4 + q;
    #pragma unroll
    for (int rt = 0; rt < 4; ++rt){
      const int r = rt*16 + c;
      float iv = acc[ci][rt].x, fv = acc[ci][rt].y;
      float gv = acc[ci][rt].z, ov = acc[ci][rt].w;
      float cp = first ? 0.f : cr[ci][rt];
      float cn = sigf(fv)*cp + sigf(iv)*tanhf_(gv);
      cr[ci][rt] = cn;
      float hn = sigf(ov)*tanhf_(cn);
      u16 a, b, cc2;
      split3(hn, a, b, cc2);
      X1[r*XSTR + j] = a; X2[r*XSTR + j] = b; X3[r*XSTR + j] = cc2;
    }
  }
}

// Post-step tail: LDS planes -> global Xg (coalesced), aval MFMA (waves 0..3),
// avalg write, hp stats -> bucketed f64 atomics.
__device__ __forceinline__ void tail_xg_aval(const KP& P, long row0,
                                             const u16* X1, const u16* X2, const u16* X3,
                                             double* redd, double* st,
                                             int tid, int lane, int wid, int blk){
  {
    int r = tid >> 3, ch = tid & 7;
    *(short8*)&P.Xg1[(row0 + r)*64 + ch*8] = *(const short8*)&X1[r*XSTR + ch*8];
    *(short8*)&P.Xg2[(row0 + r)*64 + ch*8] = *(const short8*)&X2[r*XSTR + ch*8];
    *(short8*)&P.Xg3[(row0 + r)*64 + ch*8] = *(const short8*)&X3[r*XSTR + ch*8];
  }
  if (wid < 4){
    const int c = lane & 15, q = lane >> 4, rt = wid;
    f4 av = *(const f4*)&P.hpb1[q*4];
    #pragma unroll
    for (int kc = 0; kc < 2; ++kc){
      const int aoff = (lane & 15)*64 + kc*32 + q*8;
      short8 HA1 = *(const short8*)&P.H1G[aoff];
      short8 HA2 = *(const short8*)&P.H2G[aoff];
      short8 HA3 = *(const short8*)&P.H3G[aoff];
      const int boff = (rt*16 + c)*XSTR + kc*32 + q*8;
      short8 b1 = *(const short8*)&X1[boff];
      short8 b2 = *(const short8*)&X2[boff];
      short8 b3 = *(const short8*)&X3[boff];
      MF6(HA1, HA2, HA3, b1, b2, b3, av);
    }
    #pragma unroll
    for (int i = 0; i < 4; ++i)
      P.avalg[(long)(q*4 + i)*P.B + row0 + rt*16 + c] = av[i];
    #pragma unroll
    for (int i = 0; i < 4; ++i){
      double s = (double)av[i];
      double s2 = s*s;
      #pragma unroll
      for (int off = 8; off; off >>= 1){
        s  += __shfl_down(s,  off, 16);
        s2 += __shfl_down(s2, off, 16);
      }
      if (c == 0){
        redd[wid*32 + q*4 + i]      = s;
        redd[wid*32 + 16 + q*4 + i] = s2;
      }
    }
  }
  __syncthreads();
  if (tid < 32){
    double s = redd[tid] + redd[32 + tid] + redd[64 + tid] + redd[96 + tid];
    atomicAdd(&st[(blk & (NBUCK-1))*32 + tid], s);
  }
}

// --- k_prep (merged): M = Wih@seW2, gbias; then 3-way weight/hpW1 splits ---
__global__ __launch_bounds__(256) void k_prep(KP P){
  const int g = threadIdx.x;
  {
    const float* __restrict__ wr = P.Wih + g*64;
    double gb = (double)P.bih[g] + (double)P.bhh[g];
    for (int e = 0; e < 64; ++e) gb += (double)wr[e]*(double)P.seb2[e];
    P.gbias[g] = (float)gb;
    for (int q = 0; q < 16; ++q){
      double m = 0.0;
      for (int e = 0; e < 64; ++e) m += (double)wr[e]*(double)P.seW2[e*16+q];
      P.M[g*16+q] = (float)m;
    }
  }
  __syncthreads();
  {
    const int cidx = g, gate = cidx & 3, j = cidx >> 2;
    P.gbc[cidx] = P.gbias[gate*64 + j];
    for (int k = 0; k < 96; ++k){
      float w = 0.f;
      if (k < 64)      w = P.Whh[(gate*64 + j)*64 + k];
      else if (k < 80) w = P.M[(gate*64 + j)*16 + (k - 64)];
      u16 a, b, c;
      split3(w, a, b, c);
      P.W1G[cidx*96 + k] = a;
      P.W2G[cidx*96 + k] = b;
      P.W3G[cidx*96 + k] = c;
    }
    if (cidx < 16){
      for (int k = 0; k < 64; ++k){
        u16 a, b, c;
        split3(P.hpW1[cidx*64 + k], a, b, c);
        P.H1G[cidx*64 + k] = a;
        P.H2G[cidx*64 + k] = b;
        P.H3G[cidx*64 + k] = c;
      }
    }
  }
}

// --- obs 5-moment stats over T*B ---
__global__ __launch_bounds__(512) void k_stats_mom(KP P){
  __shared__ double redd[5*9];
  const int tid = threadIdx.x, lane = tid & 63, wid = tid >> 6;
  const int row = blockIdx.x*512 + tid;
  const int B = P.B;
  const float xm = (float)P.xmax[0], ym = (float)P.ymax[0];
  double sx=0, sy=0, sxx=0, syy=0, sxy=0;
  #pragma unroll 1
  for (int t = 0; t < TT; ++t){
    float2 o = ((const float2*)P.obs)[(long)t*B + row];
    float x = o.x/xm, y = o.y/ym;
    sx += (double)x; sy += (double)y;
    sxx += (double)x*(double)x; syy += (double)y*(double)y;
    sxy += (double)x*(double)y;
  }
  #pragma unroll
  for (int off = 32; off; off >>= 1){
    sx  += __shfl_down(sx,  off, 64);
    sy  += __shfl_down(sy,  off, 64);
    sxx += __shfl_down(sxx, off, 64);
    syy += __shfl_down(syy, off, 64);
    sxy += __shfl_down(sxy, off, 64);
  }
  if (lane == 0){
    redd[0*9+wid]=sx; redd[1*9+wid]=sy; redd[2*9+wid]=sxx;
    redd[3*9+wid]=syy; redd[4*9+wid]=sxy;
  }
  __syncthreads();
  if (tid < 5){
    double s = 0.0;
    for (int w = 0; w < 8; ++w) s += redd[tid*9 + w];
    atomicAdd(&P.stats[ST_ENCM + (blockIdx.x & (NBUCK-1))*8 + tid], s);
  }
}

// --- k_enc: 8 encode steps; A-frags REGISTER-RESIDENT across t-loop (R8);
//     X planes LDS; c in regs; tail writes Xg + avalg + hp stats for d=0. ---
__global__ __launch_bounds__(512) void k_enc(KP P){
  __shared__ __align__(16) u16 X1[ROWS*XSTR];
  __shared__ __align__(16) u16 X2[ROWS*XSTR];
  __shared__ __align__(16) u16 X3[ROWS*XSTR];
  __shared__ float sef[48];
  __shared__ double redd[128];
  const int tid = threadIdx.x, lane = tid & 63, wid = tid >> 6;
  const int B = P.B;
  const long row0 = (long)blockIdx.x * ROWS;
  const float xm = (float)P.xmax[0], ym = (float)P.ymax[0];
  const int c = lane & 15, q = lane >> 4;

  // hoisted weight A-fragments + bias (step-invariant)
  short8 A1r[2][3], A2r[2][3], A3r[2][3];
  f4 biasr[2];
  #pragma unroll
  for (int ci = 0; ci < 2; ++ci){
    const int crow = (2*wid + ci)*16 + c;
    #pragma unroll
    for (int kc = 0; kc < 3; ++kc){
      const int aoff = crow*96 + kc*32 + q*8;
      A1r[ci][kc] = *(const short8*)&P.W1G[aoff];
      A2r[ci][kc] = *(const short8*)&P.W2G[aoff];
      A3r[ci][kc] = *(const short8*)&P.W3G[aoff];
    }
    biasr[ci] = *(const f4*)&P.gbc[(2*wid + ci)*16 + q*4];
  }

  for (int m = tid; m < (ROWS*XSTR)/2; m += 512){
    ((unsigned*)X1)[m] = 0u; ((unsigned*)X2)[m] = 0u; ((unsigned*)X3)[m] = 0u;
  }
  fold_se_mom(P, P.stats + ST_ENCM, 8.0*(double)B, sef, tid);
  __syncthreads();

  if (tid < ROWS){
    float2 o = ((const float2*)P.obs)[row0 + tid];
    float p0 = o.x/xm, p1 = o.y/ym;
    #pragma unroll
    for (int qq = 0; qq < 16; ++qq){
      float tv = sef[qq]*p0 + sef[16+qq]*p1 + sef[32+qq];
      tv = tv > 0.f ? tv : 0.f;
      u16 a, b, cc;
      split3(tv, a, b, cc);
      X1[tid*XSTR + 64 + qq] = a; X2[tid*XSTR + 64 + qq] = b; X3[tid*XSTR + 64 + qq] = cc;
    }
  }
  __syncthreads();

  float cr[2][4];
  f4 acc[2][4];

  #pragma unroll 1
  for (int t = 0; t < TT; ++t){
    #pragma unroll
    for (int ci = 0; ci < 2; ++ci)
      #pragma unroll
      for (int rt = 0; rt < 4; ++rt) acc[ci][rt] = biasr[ci];
    #pragma unroll
    for (int rt = 0; rt < 4; ++rt){
      #pragma unroll
      for (int kc = 0; kc < 3; ++kc){
        const int boff = (rt*16 + c)*XSTR + kc*32 + q*8;
        short8 b1 = *(const short8*)&X1[boff];
        short8 b2 = *(const short8*)&X2[boff];
        short8 b3 = *(const short8*)&X3[boff];
        #pragma unroll
        for (int ci = 0; ci < 2; ++ci){
          MF6(A1r[ci][kc], A2r[ci][kc], A3r[ci][kc], b1, b2, b3, acc[ci][rt]);
        }
      }
    }
    __syncthreads();
    do_epilogue(acc, cr, X1, X2, X3, t == 0, lane, wid);
    if (t < TT-1 && tid < ROWS){
      float2 o = ((const float2*)P.obs)[(long)(t+1)*B + row0 + tid];
      float p0 = o.x/xm, p1 = o.y/ym;
      #pragma unroll
      for (int qq = 0; qq < 16; ++qq){
        float tv = sef[qq]*p0 + sef[16+qq]*p1 + sef[32+qq];
        tv = tv > 0.f ? tv : 0.f;
        u16 a, b, cc;
        split3(tv, a, b, cc);
        X1[tid*XSTR + 64 + qq] = a; X2[tid*XSTR + 64 + qq] = b; X3[tid*XSTR + 64 + qq] = cc;
      }
    }
    __syncthreads();
  }

  #pragma unroll
  for (int ci = 0; ci < 2; ++ci){
    const int j = (2*wid + ci)*4 + q;
    #pragma unroll
    for (int rt = 0; rt < 4; ++rt)
      P.c[(long)j*B + row0 + rt*16 + c] = cr[ci][rt];
  }
  tail_xg_aval(P, row0, X1, X2, X3, redd, P.stats + ST_HP(0), tid, lane, wid, blockIdx.x);
}

// --- k_dec_pos: thin elementwise head from avalg (512 thr) ---
template<bool FIRSTD>
__global__ __launch_bounds__(512) void k_dec_pos(KP P, int d){
  __shared__ float hpf[32];
  __shared__ double redd[5*9];
  const int tid = threadIdx.x, lane = tid & 63, wid = tid >> 6;
  const int B = P.B;
  const int row = blockIdx.x*512 + tid;
  if (tid < 16){
    const double* st = P.stats + ST_HP(d);
    double s = 0.0, s2 = 0.0;
    for (int b = 0; b < NBUCK; ++b){ s += st[b*32 + tid]; s2 += st[b*32 + 16 + tid]; }
    double invN = 1.0/(double)B;
    double mu = s*invN, var = s2*invN - mu*mu;
    float sc = rsqrtf((float)var + 1e-5f) * P.hpg[tid];
    hpf[tid] = sc;
    hpf[16+tid] = P.hpbeta[tid] - (float)mu*sc;
  }
  __syncthreads();

  float r0v = P.hpb2[0], r1v = P.hpb2[1];
  #pragma unroll
  for (int qq = 0; qq < 16; ++qq){
    float a = P.avalg[(long)qq*B + row];
    a = a*hpf[qq] + hpf[16+qq];
    a = a > 0.f ? a : 0.f;
    r0v += a*P.hpW2[qq]; r1v += a*P.hpW2[16+qq];
  }
  const float xm = (float)P.xmax[0], ym = (float)P.ymax[0];
  float l0, l1;
  if constexpr (FIRSTD){
    float2 o = ((const float2*)P.obs)[(long)(TT-1)*B + row];
    l0 = o.x/xm; l1 = o.y/ym;
  } else {
    float2 lp = ((const float2*)P.lastpos)[row];
    l0 = lp.x; l1 = lp.y;
  }
  l0 = sigf(r0v + l0);
  l1 = sigf(r1v + l1);
  ((float2*)P.lastpos)[row] = make_float2(l0, l1);
  ((float2*)P.out)[(long)d*B + row] = make_float2(l0*xm, l1*ym);

  double a0=l0, a1=l1, a2=(double)l0*(double)l0, a3=(double)l1*(double)l1, a4=(double)l0*(double)l1;
  #pragma unroll
  for (int off = 32; off; off >>= 1){
    a0 += __shfl_down(a0, off, 64); a1 += __shfl_down(a1, off, 64);
    a2 += __shfl_down(a2, off, 64); a3 += __shfl_down(a3, off, 64);
    a4 += __shfl_down(a4, off, 64);
  }
  if (lane == 0){
    redd[0*9+wid]=a0; redd[1*9+wid]=a1; redd[2*9+wid]=a2;
    redd[3*9+wid]=a3; redd[4*9+wid]=a4;
  }
  __syncthreads();
  if (tid < 5){
    double s = 0.0;
    for (int w = 0; w < 8; ++w) s += redd[tid*9 + w];
    atomicAdd(&P.stats[ST_MOM(d) + (blockIdx.x & (NBUCK-1))*8 + tid], s);
  }
}

// --- k_dec_lstm: B-frags direct from global Xg; v in-lane; c in regs ---
template<int DUMMY>
__global__ __launch_bounds__(512) void k_dec_lstm(KP P, int d){
  __shared__ __align__(16) u16 X1[ROWS*XSTR];
  __shared__ __align__(16) u16 X2[ROWS*XSTR];
  __shared__ __align__(16) u16 X3[ROWS*XSTR];
  __shared__ float sef[48];
  __shared__ double redd[128];
  const int tid = threadIdx.x, lane = tid & 63, wid = tid >> 6;
  const int B = P.B;
  const long row0 = (long)blockIdx.x * ROWS;
  const int c = lane & 15, q = lane >> 4;

  fold_se_mom(P, P.stats + ST_MOM(d), (double)B, sef, tid);
  __syncthreads();

  // in-lane v fragments for kc=2 (k=64..79 from lastpos; 80..95 zero)
  short8 vb1[4], vb2[4], vb3[4];
  {
    const short8 z = {0,0,0,0,0,0,0,0};
    #pragma unroll
    for (int rt = 0; rt < 4; ++rt){ vb1[rt] = z; vb2[rt] = z; vb3[rt] = z; }
    if (q < 2){
      #pragma unroll
      for (int rt = 0; rt < 4; ++rt){
        float2 lp = ((const float2*)P.lastpos)[row0 + rt*16 + c];
        U8 u1, u2, u3;
        #pragma unroll
        for (int j = 0; j < 8; ++j){
          const int ch = q*8 + j;
          float tv = sef[ch]*lp.x + sef[16+ch]*lp.y + sef[32+ch];
          tv = tv > 0.f ? tv : 0.f;
          split3(tv, u1.u[j], u2.u[j], u3.u[j]);
        }
        vb1[rt] = u1.v; vb2[rt] = u2.v; vb3[rt] = u3.v;
      }
    }
  }
  // prefetch c
  float cr[2][4];
  #pragma unroll
  for (int ci = 0; ci < 2; ++ci){
    const int j = (2*wid + ci)*4 + q;
    #pragma unroll
    for (int rt = 0; rt < 4; ++rt)
      cr[ci][rt] = P.c[(long)j*B + row0 + rt*16 + c];
  }

  // gate GEMM: h-part B-frags DIRECT from global planes
  f4 acc[2][4];
  #pragma unroll
  for (int ci = 0; ci < 2; ++ci){
    f4 bias = *(const f4*)&P.gbc[(2*wid + ci)*16 + q*4];
    #pragma unroll
    for (int rt = 0; rt < 4; ++rt) acc[ci][rt] = bias;
  }
  #pragma unroll
  for (int rt = 0; rt < 4; ++rt){
    const long gb = (row0 + rt*16 + c)*64;
    #pragma unroll
    for (int kc = 0; kc < 2; ++kc){
      short8 b1 = *(const short8*)&P.Xg1[gb + kc*32 + q*8];
      short8 b2 = *(const short8*)&P.Xg2[gb + kc*32 + q*8];
      short8 b3 = *(const short8*)&P.Xg3[gb + kc*32 + q*8];
      #pragma unroll
      for (int ci = 0; ci < 2; ++ci){
        const int aoff = ((2*wid + ci)*16 + c)*96 + kc*32 + q*8;
        short8 A1 = *(const short8*)&P.W1G[aoff];
        short8 A2 = *(const short8*)&P.W2G[aoff];
        short8 A3 = *(const short8*)&P.W3G[aoff];
        MF6(A1, A2, A3, b1, b2, b3, acc[ci][rt]);
      }
    }
    #pragma unroll
    for (int ci = 0; ci < 2; ++ci){
      const int aoff = ((2*wid + ci)*16 + c)*96 + 2*32 + q*8;
      short8 A1 = *(const short8*)&P.W1G[aoff];
      short8 A2 = *(const short8*)&P.W2G[aoff];
      short8 A3 = *(const short8*)&P.W3G[aoff];
      MF6(A1, A2, A3, vb1[rt], vb2[rt], vb3[rt], acc[ci][rt]);
    }
  }

  do_epilogue(acc, cr, X1, X2, X3, false, lane, wid);
  #pragma unroll
  for (int ci = 0; ci < 2; ++ci){
    const int j = (2*wid + ci)*4 + q;
    #pragma unroll
    for (int rt = 0; rt < 4; ++rt)
      P.c[(long)j*B + row0 + rt*16 + c] = cr[ci][rt];
  }
  __syncthreads();
  tail_xg_aval(P, row0, X1, X2, X3, redd, P.stats + ST_HP(d+1), tid, lane, wid, blockIdx.x);
}

extern "C" void kernel_launch(void* const* d_in, const int* in_sizes, int n_in,
                              void* d_out, int out_size, void* d_ws, size_t ws_size,
                              hipStream_t stream){
  KP P;
  P.obs    = (const float*)d_in[0];
  P.seW1   = (const float*)d_in[1];
  P.seb1   = (const float*)d_in[2];
  P.seg    = (const float*)d_in[3];
  P.sebeta = (const float*)d_in[4];
  P.seW2   = (const float*)d_in[5];
  P.seb2   = (const float*)d_in[6];
  P.hpW1   = (const float*)d_in[7];
  P.hpb1   = (const float*)d_in[8];
  P.hpg    = (const float*)d_in[9];
  P.hpbeta = (const float*)d_in[10];
  P.hpW2   = (const float*)d_in[11];
  P.hpb2   = (const float*)d_in[12];
  P.Wih    = (const float*)d_in[13];
  P.Whh    = (const float*)d_in[14];
  P.bih    = (const float*)d_in[15];
  P.bhh    = (const float*)d_in[16];
  P.xmax   = (const int*)d_in[17];
  P.ymax   = (const int*)d_in[18];
  // d_in[19] = pred_len (fixed 12)

  const int B = in_sizes[0] / (TT*2);   // 131072
  P.B = B;
  float* ws = (float*)d_ws;
  // float-slot offsets. Xg plane = B*64 u16 = 32B float-slots. ~93.6 MB total.
  P.Xg1     = (u16*)(ws);
  P.Xg2     = (u16*)(ws + (size_t)32*B);
  P.c       = ws + (size_t)64*B;                   // [64][B] f32
  P.lastpos = ws + (size_t)128*B;                  // [B][2]
  P.Xg3     = (u16*)(ws + (size_t)130*B);
  P.avalg   = ws + (size_t)162*B;                  // [16][B]
  float* tail = ws + (size_t)178*B;
  P.M     = tail;                          // 4096
  P.gbias = tail + 4096;                   // 256
  P.gbc   = tail + 4352;                   // 256
  // W planes: 256*96 u16 = 12288 float-slots each (R11-verified offsets)
  P.W1G   = (u16*)(tail + 4608);
  P.W2G   = (u16*)(tail + 4608 + 12288);
  P.W3G   = (u16*)(tail + 4608 + 24576);
  // H planes: 16*64 u16 = 512 float-slots each
  P.H1G   = (u16*)(tail + 4608 + 36864);
  P.H2G   = (u16*)(tail + 4608 + 37376);
  P.H3G   = (u16*)(tail + 4608 + 37888);
  P.stats = (double*)(tail + 4608 + 38400);  // 7808 doubles
  P.out   = (float*)d_out;

  hipMemsetAsync(P.stats, 0, ST_TOTAL*sizeof(double), stream);

  k_prep     <<<1, 256, 0, stream>>>(P);
  k_stats_mom<<<B/512, 512, 0, stream>>>(P);
  k_enc      <<<B/ROWS, 512, 0, stream>>>(P);

  for (int d = 0; d < PLEN; ++d){
    if (d == 0) k_dec_pos<true ><<<B/512, 512, 0, stream>>>(P, d);
    else        k_dec_pos<false><<<B/512, 512, 0, stream>>>(P, d);
    if (d < PLEN-1) k_dec_lstm<0><<<B/ROWS, 512, 0, stream>>>(P, d);
  }
}